// Round 1
// baseline (1116.598 us; speedup 1.0000x reference)
//
#include <hip/hip_runtime.h>

typedef __attribute__((ext_vector_type(8))) short s16x8;
typedef __attribute__((ext_vector_type(4))) float f32x4;
typedef __attribute__((ext_vector_type(4))) unsigned short u16x4;

__device__ __forceinline__ unsigned short f2bf(float f){
  unsigned u = __float_as_uint(f);
  u += 0x7fffu + ((u >> 16) & 1u);   // RNE
  return (unsigned short)(u >> 16);
}

// x0 [16384,256] f32 -> XT [256,16384] bf16
__global__ void xpose_cvt(const float* __restrict__ src, unsigned short* __restrict__ dst){
  __shared__ float tile[64][65];
  const int R0 = blockIdx.x * 64;
  const int C0 = blockIdx.y * 64;
  const int t = threadIdx.x;
  #pragma unroll
  for (int i = 0; i < 16; ++i){
    int id = i * 256 + t; int r = id >> 6, c = id & 63;
    tile[r][c] = src[(size_t)(R0 + r) * 256 + (C0 + c)];
  }
  __syncthreads();
  #pragma unroll
  for (int i = 0; i < 16; ++i){
    int id = i * 256 + t; int c = id >> 6, r = id & 63;
    dst[(size_t)(C0 + c) * 16384 + (R0 + r)] = f2bf(tile[r][c]);
  }
}

__global__ void cvt_k(const float* __restrict__ src, unsigned short* __restrict__ dst, int n){
  int i = (blockIdx.x * 256 + threadIdx.x) * 4;
  if (i + 3 < n){
    float4 v = *(const float4*)(src + i);
    u16x4 o; o.x = f2bf(v.x); o.y = f2bf(v.y); o.z = f2bf(v.z); o.w = f2bf(v.w);
    *(u16x4*)(dst + i) = o;
  }
}

// C[M,BN] = A[M,K] @ B^T   (B stored as [BN,K] bf16, K-contiguous)
// AMODE: 0 = A fp32 (convert in-flight), 1 = A bf16, 2 = A bf16 + row gather
// EPI:   0 = bf16 row-major store
//        1 = bias+relu, bf16 TRANSPOSED store (dst[col*M + row])
//        2 = bias+relu, bf16 row-major
//        3 = bias+relu, fp32 row-major
template<int BN, int AMODE, int EPI>
__global__ __launch_bounds__(512, 2)
void gemm_k(const void* __restrict__ Asrc, const unsigned short* __restrict__ Bsrc,
            const float* __restrict__ bias, const int* __restrict__ gidx,
            void* __restrict__ Cdst, const int M, const int Kd)
{
  constexpr int NF = BN / 64;      // n-frags per wave
  constexpr int BITER = BN / 64;   // B staging iterations
  __shared__ __align__(16) unsigned short Alds[2][64 * 64];
  __shared__ __align__(16) unsigned short Blds[2][BN * 64];

  const int tid  = threadIdx.x;
  const int lane = tid & 63;
  const int wv   = tid >> 6;
  const int wm   = wv >> 2;        // 0..1
  const int wn   = wv & 3;         // 0..3
  const int row0 = blockIdx.x * 64;
  const int fr = lane & 15, fq = lane >> 4;

  const int r_st = tid >> 3;       // 0..63
  const int c_st = tid & 7;        // 0..7 (16B chunk within 64-elem row)

  size_t arow;
  if (AMODE == 2) arow = (size_t)gidx[row0 + r_st];
  else            arow = (size_t)(row0 + r_st);

  f32x4 acc[2][NF];
  #pragma unroll
  for (int m = 0; m < 2; ++m)
    #pragma unroll
    for (int n = 0; n < NF; ++n)
      acc[m][n] = f32x4{0.f, 0.f, 0.f, 0.f};

  float4 aR0, aR1; s16x8 aB;
  s16x8 bR[BITER];

  auto loadAB = [&](int k0){
    if constexpr (AMODE == 0){
      const float* p = (const float*)Asrc + arow * (size_t)Kd + (k0 + c_st * 8);
      aR0 = *(const float4*)p;
      aR1 = *(const float4*)(p + 4);
    } else {
      const unsigned short* p = (const unsigned short*)Asrc + arow * (size_t)Kd + (k0 + c_st * 8);
      aB = *(const s16x8*)p;
    }
    #pragma unroll
    for (int i = 0; i < BITER; ++i){
      const unsigned short* p = Bsrc + (size_t)(r_st + i * 64) * Kd + (k0 + c_st * 8);
      bR[i] = *(const s16x8*)p;
    }
  };
  auto writeAB = [&](int buf){
    s16x8 w;
    if constexpr (AMODE == 0){
      w[0] = (short)f2bf(aR0.x); w[1] = (short)f2bf(aR0.y); w[2] = (short)f2bf(aR0.z); w[3] = (short)f2bf(aR0.w);
      w[4] = (short)f2bf(aR1.x); w[5] = (short)f2bf(aR1.y); w[6] = (short)f2bf(aR1.z); w[7] = (short)f2bf(aR1.w);
    } else {
      w = aB;
    }
    *(s16x8*)&Alds[buf][r_st * 64 + ((c_st ^ (r_st & 7)) * 8)] = w;
    #pragma unroll
    for (int i = 0; i < BITER; ++i){
      int rB = r_st + i * 64;
      *(s16x8*)&Blds[buf][rB * 64 + ((c_st ^ (rB & 7)) * 8)] = bR[i];
    }
  };

  const int nsteps = Kd / 64;
  loadAB(0);
  writeAB(0);
  __syncthreads();
  int buf = 0;
  for (int s = 0; s < nsteps; ++s){
    if (s + 1 < nsteps) loadAB((s + 1) * 64);

    s16x8 af[2][2], bfr[NF][2];
    #pragma unroll
    for (int m = 0; m < 2; ++m)
      #pragma unroll
      for (int kc = 0; kc < 2; ++kc){
        int row = wm * 32 + m * 16 + fr;
        int c = kc * 4 + fq;
        af[m][kc] = *(const s16x8*)&Alds[buf][row * 64 + ((c ^ (row & 7)) * 8)];
      }
    #pragma unroll
    for (int n = 0; n < NF; ++n)
      #pragma unroll
      for (int kc = 0; kc < 2; ++kc){
        int col = wn * (BN / 4) + n * 16 + fr;
        int c = kc * 4 + fq;
        bfr[n][kc] = *(const s16x8*)&Blds[buf][col * 64 + ((c ^ (col & 7)) * 8)];
      }
    #pragma unroll
    for (int kc = 0; kc < 2; ++kc)
      #pragma unroll
      for (int m = 0; m < 2; ++m)
        #pragma unroll
        for (int n = 0; n < NF; ++n)
          acc[m][n] = __builtin_amdgcn_mfma_f32_16x16x32_bf16(af[m][kc], bfr[n][kc], acc[m][n], 0, 0, 0);

    if (s + 1 < nsteps) writeAB(buf ^ 1);
    __syncthreads();
    buf ^= 1;
  }

  // epilogue: C frag layout col = lane&15, row = (lane>>4)*4 + j
  #pragma unroll
  for (int m = 0; m < 2; ++m){
    int rowb = row0 + wm * 32 + m * 16 + fq * 4;
    #pragma unroll
    for (int n = 0; n < NF; ++n){
      int col = wn * (BN / 4) + n * 16 + fr;
      f32x4 v = acc[m][n];
      if constexpr (EPI == 0){
        unsigned short* o = (unsigned short*)Cdst;
        #pragma unroll
        for (int j = 0; j < 4; ++j) o[(size_t)(rowb + j) * BN + col] = f2bf(v[j]);
      } else if constexpr (EPI == 1){
        float b = bias[col];
        u16x4 w;
        #pragma unroll
        for (int j = 0; j < 4; ++j) w[j] = f2bf(fmaxf(v[j] + b, 0.f));
        *(u16x4*)((unsigned short*)Cdst + (size_t)col * M + rowb) = w;
      } else if constexpr (EPI == 2){
        float b = bias[col];
        unsigned short* o = (unsigned short*)Cdst;
        #pragma unroll
        for (int j = 0; j < 4; ++j) o[(size_t)(rowb + j) * BN + col] = f2bf(fmaxf(v[j] + b, 0.f));
      } else {
        float b = bias[col];
        float* o = (float*)Cdst;
        #pragma unroll
        for (int j = 0; j < 4; ++j) o[(size_t)(rowb + j) * BN + col] = fmaxf(v[j] + b, 0.f);
      }
    }
  }
}

// out[i] = softmax(encode[i] @ W2^T + b2), one wave per row
__global__ void mlp2_k(const float* __restrict__ enc, const float* __restrict__ W2,
                       const float* __restrict__ b2, float* __restrict__ out){
  int gw = (int)((blockIdx.x * blockDim.x + threadIdx.x) >> 6);   // global wave = row
  int lane = threadIdx.x & 63;
  if (gw >= 8192) return;
  int c = lane & 15, q = lane >> 4;
  const float* e = enc + (size_t)gw * 128 + q * 32;
  const float* w = W2 + c * 128 + q * 32;
  float s = 0.f;
  #pragma unroll
  for (int k = 0; k < 32; ++k) s += e[k] * w[k];
  s += __shfl_xor(s, 16);
  s += __shfl_xor(s, 32);
  s += b2[c];
  float mx = s;
  #pragma unroll
  for (int d = 1; d < 16; d <<= 1) mx = fmaxf(mx, __shfl_xor(mx, d));
  float ex = __expf(s - mx);
  float sm = ex;
  #pragma unroll
  for (int d = 1; d < 16; d <<= 1) sm += __shfl_xor(sm, d);
  float r = ex / sm;
  if (q == 0) out[(size_t)gw * 16 + c] = r;
}

extern "C" void kernel_launch(void* const* d_in, const int* in_sizes, int n_in,
                              void* d_out, int out_size, void* d_ws, size_t ws_size,
                              hipStream_t stream) {
  const float* A  = (const float*)d_in[0];   // [16384,16384]
  const float* x0 = (const float*)d_in[1];   // [16384,256]
  const float* gw = (const float*)d_in[2];   // [3,256,256]
  const float* gb = (const float*)d_in[3];   // [3,256]
  const float* w1 = (const float*)d_in[4];   // [128,256]
  const float* b1 = (const float*)d_in[5];   // [128]
  const float* w2 = (const float*)d_in[6];   // [16,128]
  const float* b2 = (const float*)d_in[7];   // [16]
  const int*  idx = (const int*)d_in[8];     // [8192]
  float* out = (float*)d_out;

  char* ws = (char*)d_ws;
  unsigned short* xbT = (unsigned short*)ws;                       // 256*16384 bf16 (8 MiB)
  unsigned short* t   = (unsigned short*)(ws + (8u  << 20));       // 16384*256 bf16 (8 MiB)
  unsigned short* x3b = (unsigned short*)(ws + (16u << 20));       // 16384*256 bf16 (8 MiB)
  unsigned short* wgb = (unsigned short*)(ws + (24u << 20));       // 3*256*256 bf16
  unsigned short* w1b = (unsigned short*)(ws + (24u << 20) + 3 * 65536 * 2); // 128*256 bf16

  xpose_cvt<<<dim3(256, 4), 256, 0, stream>>>(x0, xbT);
  cvt_k<<<192, 256, 0, stream>>>(gw, wgb, 3 * 65536);
  cvt_k<<<32, 256, 0, stream>>>(w1, w1b, 128 * 256);

  for (int l = 0; l < 3; ++l){
    // t = A @ X   (A fp32 streamed+converted, X^T bf16 panels)
    gemm_k<256, 0, 0><<<256, 512, 0, stream>>>(A, xbT, nullptr, nullptr, t, 16384, 16384);
    if (l < 2){
      // X_next^T = relu(t @ W_l^T + b_l)^T
      gemm_k<256, 1, 1><<<256, 512, 0, stream>>>(t, wgb + l * 65536, gb + l * 256, nullptr, xbT, 16384, 256);
    } else {
      // x3 (row-major) = relu(t @ W_2^T + b_2)
      gemm_k<256, 1, 2><<<256, 512, 0, stream>>>(t, wgb + 2 * 65536, gb + 2 * 256, nullptr, x3b, 16384, 256);
    }
  }
  // encode = relu(x3[idx] @ W1^T + b1) -> d_out (fp32)
  gemm_k<128, 2, 3><<<128, 512, 0, stream>>>(x3b, w1b, b1, idx, out, 8192, 256);
  // out = softmax(encode @ W2^T + b2)
  mlp2_k<<<2048, 256, 0, stream>>>(out, w2, b2, out + (size_t)8192 * 128);
}